// Round 14
// baseline (665.880 us; speedup 1.0000x reference)
//
#include <hip/hip_runtime.h>
#include <math.h>

#define TT 16
#define BB 32
#define NN 256
#define DD 128
#define NSTEPS 5
#define SKIPF 0.3f
#define EPSF 1e-8f
// truncated scan: timesteps t < T0 contribute <= ~2e-5 to A_15 -- 400x below
// tolerance. Verified R18: absmax unchanged.
#define T0 7
#define TBLIVE ((TT - T0) * BB)    // 288 live (t,b) pairs

// R17: FAILED cross-XCD barrier fusion (45us/barrier). R18: truncated scan.
// R20: 295.9us; 5 dependent k_step dispatches ~33us each (~165us).
// R21: k_gru5 fusion FAILED correctness: double batch offset in h write
//   (b=0 correct, rest corrupted, absmax 15). Structure itself RAN fine.
// R22: one-expression fix (write hOut + (col<<8) + n0). Bench died on an
//   ACQUISITION-level infra fault (no timing, no pytest) -- same signature
//   as R14, which bisection (R15) proved was not the kernel.
// R23 (this round): identical resubmit of R22.

typedef __attribute__((ext_vector_type(8))) short bf16x8;
typedef __attribute__((ext_vector_type(4))) float f32x4;
typedef __attribute__((ext_vector_type(8))) _Float16 half8;
typedef __attribute__((ext_vector_type(2))) _Float16 h2;

__device__ __forceinline__ unsigned short f2bf(float f) {
    union { float f; unsigned u; } v; v.f = f;
    unsigned r = (v.u + 0x7FFF + ((v.u >> 16) & 1)) >> 16;
    return (unsigned short)r;
}
__device__ __forceinline__ float bf2f(unsigned short u) {
    union { unsigned u; float f; } v; v.u = ((unsigned)u) << 16; return v.f;
}
__device__ __forceinline__ unsigned pack2(unsigned short a, unsigned short b) {
    return (unsigned)a | ((unsigned)b << 16);
}
__device__ __forceinline__ unsigned pkrtz(float a, float b) {
    unsigned r;
    asm("v_cvt_pkrtz_f16_f32 %0, %1, %2" : "=v"(r) : "v"(a), "v"(b));
    return r;
}
__device__ __forceinline__ h2 u2h(unsigned u) {
    union { unsigned u; h2 h; } v; v.u = u; return v.h;
}
__device__ __forceinline__ float sigmoidf_(float x) {
    return 1.0f / (1.0f + __expf(-x));
}
__device__ __forceinline__ float tanhf_(float x) {
    return 1.0f - 2.0f / (__expf(2.0f * x) + 1.0f);
}
// load 8 f32 at src, convert to packed f16 half8
__device__ __forceinline__ half8 ld8f32h(const float* src) {
    float4 a = *(const float4*)src;
    float4 b = *(const float4*)(src + 4);
    uint4 o;
    o.x = pkrtz(a.x, a.y); o.y = pkrtz(a.z, a.w);
    o.z = pkrtz(b.x, b.y); o.w = pkrtz(b.z, b.w);
    union { uint4 u; half8 h; } v; v.u = o; return v.h;
}

// ---------------------------------------------------------------------------
// gram2 (f16 packed, 64x64 wave tiles, in-block norms, f32 direct input) —
// VERIFIED R20. grid = 4 rg x TBLIVE = 1152 blocks, 256 threads.
// ---------------------------------------------------------------------------
#define IVSTR 257
__global__ __launch_bounds__(256, 2) void k_gram2(const float* __restrict__ x,
                                                  const float* __restrict__ Wgl,
                                                  unsigned short* __restrict__ attn) {
    int bid = blockIdx.x;
    int rg = bid / TBLIVE;              // 0..3
    int tb = T0 * BB + (bid - rg * TBLIVE);
    int n0 = rg << 6;
    int tid = threadIdx.x;
    int wave = tid >> 6, lane = tid & 63;
    int m16 = lane & 15, quad = lane >> 4;
    int wcol = wave << 6;

    __shared__ unsigned wS[16 * 64];
    __shared__ unsigned ivS[16 * IVSTR];
    __shared__ float rsum[4][64];

    const float* Xb = x + ((size_t)tb << 15);

    #pragma unroll
    for (int k = 0; k < 4; ++k) {
        int idx = (tid << 2) + k;
        float2 wv = *(const float2*)(Wgl + ((idx >> 6) << 7) + ((idx & 63) << 1));
        wS[idx] = pkrtz(wv.x * wv.x, wv.y * wv.y);
    }

    half8 Bf[4][4];
    #pragma unroll
    for (int ks = 0; ks < 4; ++ks)
        #pragma unroll
        for (int cb = 0; cb < 4; ++cb)
            Bf[ks][cb] = ld8f32h(Xb + ((wcol + (cb << 4) + m16) << 7) + (ks << 5) + (quad << 3));

    half8 Af[4][4];
    #pragma unroll
    for (int rb = 0; rb < 4; ++rb)
        #pragma unroll
        for (int ks = 0; ks < 4; ++ks)
            Af[rb][ks] = ld8f32h(Xb + ((n0 + (rb << 4) + m16) << 7) + (ks << 5) + (quad << 3));

    f32x4 att[4][4];
    #pragma unroll
    for (int rb = 0; rb < 4; ++rb)
        #pragma unroll
        for (int cb = 0; cb < 4; ++cb) att[rb][cb] = (f32x4){0.f, 0.f, 0.f, 0.f};

    __syncthreads();

    union H8 { half8 v; h2 p[4]; };

    {
        half8 w2f[4];
        #pragma unroll
        for (int ks = 0; ks < 4; ++ks)
            w2f[ks] = *(const half8*)((const unsigned short*)wS + (m16 << 7) + (ks << 5) + (quad << 3));
        #pragma unroll
        for (int cb = 0; cb < 4; ++cb) {
            f32x4 nacc = (f32x4){0.f, 0.f, 0.f, 0.f};
            #pragma unroll
            for (int ks = 0; ks < 4; ++ks) {
                H8 bb; bb.v = Bf[ks][cb];
                H8 sq;
                sq.p[0] = bb.p[0] * bb.p[0];
                sq.p[1] = bb.p[1] * bb.p[1];
                sq.p[2] = bb.p[2] * bb.p[2];
                sq.p[3] = bb.p[3] * bb.p[3];
                nacc = __builtin_amdgcn_mfma_f32_16x16x32_f16(sq.v, w2f[ks], nacc, 0, 0, 0);
            }
            #pragma unroll
            for (int r = 0; r < 4; ++r) {
                float inv = 1.0f / (sqrtf(nacc[r]) + EPSF);
                ivS[m16 * IVSTR + wcol + (cb << 4) + (quad << 2) + r] = pkrtz(inv, inv);
            }
        }
    }
    __syncthreads();

    #pragma unroll 1
    for (int h = 0; h < 16; ++h) {
        const unsigned* ivh = ivS + h * IVSTR;
        h2 ivr[4], ivc[4];
        #pragma unroll
        for (int rb = 0; rb < 4; ++rb) ivr[rb] = u2h(ivh[n0 + (rb << 4) + m16]);
        #pragma unroll
        for (int cb = 0; cb < 4; ++cb) ivc[cb] = u2h(ivh[wcol + (cb << 4) + m16]);

        #pragma unroll
        for (int ks = 0; ks < 4; ++ks) {
            uint4 wu = *(const uint4*)(wS + (h << 6) + (ks << 4) + (quad << 2));
            h2 w0 = u2h(wu.x), w1 = u2h(wu.y), w2 = u2h(wu.z), w3 = u2h(wu.w);

            H8 afr[4];
            #pragma unroll
            for (int rb = 0; rb < 4; ++rb) {
                H8 a; a.v = Af[rb][ks];
                h2 s = ivr[rb];
                afr[rb].p[0] = a.p[0] * (w0 * s);
                afr[rb].p[1] = a.p[1] * (w1 * s);
                afr[rb].p[2] = a.p[2] * (w2 * s);
                afr[rb].p[3] = a.p[3] * (w3 * s);
            }
            #pragma unroll
            for (int cb = 0; cb < 4; ++cb) {
                H8 b; b.v = Bf[ks][cb];
                H8 bf;
                bf.p[0] = b.p[0] * ivc[cb];
                bf.p[1] = b.p[1] * ivc[cb];
                bf.p[2] = b.p[2] * ivc[cb];
                bf.p[3] = b.p[3] * ivc[cb];
                #pragma unroll
                for (int rb = 0; rb < 4; ++rb)
                    att[rb][cb] = __builtin_amdgcn_mfma_f32_16x16x32_f16(afr[rb].v, bf.v, att[rb][cb], 0, 0, 0);
            }
        }
    }

    float rs[4][4];
    #pragma unroll
    for (int rb = 0; rb < 4; ++rb)
        #pragma unroll
        for (int r = 0; r < 4; ++r) {
            float s = 0.f;
            #pragma unroll
            for (int cb = 0; cb < 4; ++cb) {
                float v = fmaxf(att[rb][cb][r], 0.0f);
                att[rb][cb][r] = v;
                s += v;
            }
            rs[rb][r] = s;
        }
    #pragma unroll
    for (int m = 1; m < 16; m <<= 1)
        #pragma unroll
        for (int rb = 0; rb < 4; ++rb)
            #pragma unroll
            for (int r = 0; r < 4; ++r)
                rs[rb][r] += __shfl_xor(rs[rb][r], m, 64);
    if (m16 == 0) {
        #pragma unroll
        for (int rb = 0; rb < 4; ++rb)
            #pragma unroll
            for (int r = 0; r < 4; ++r)
                rsum[wave][(rb << 4) + (quad << 2) + r] = rs[rb][r];
    }
    __syncthreads();

    unsigned short* outb = attn + ((size_t)tb << 16);
    #pragma unroll
    for (int rb = 0; rb < 4; ++rb) {
        #pragma unroll
        for (int r = 0; r < 4; ++r) {
            int row = (rb << 4) + (quad << 2) + r;
            float tot = rsum[0][row] + rsum[1][row] + rsum[2][row] + rsum[3][row];
            float inv = (1.0f - SKIPF) / (tot + 16.0f * EPSF);
            #pragma unroll
            for (int cb = 0; cb < 4; ++cb) {
                int col = wcol + (cb << 4) + m16;
                outb[((size_t)(n0 + row) << 8) + col] = f2bf(att[rb][cb][r] * inv);
            }
        }
    }
}

// ---------------------------------------------------------------------------
// scanh: blocks 0..2047: truncated scan -> Afin bf16.
//        blocks 2048..2175: bf16-transposed GRU weights (wprep).
// ---------------------------------------------------------------------------
__global__ __launch_bounds__(256) void k_scanh(const float* __restrict__ supports,
                                               const unsigned short* __restrict__ AttA,
                                               const float* __restrict__ Wa,
                                               const float* __restrict__ Wr,
                                               const float* __restrict__ Wz,
                                               const float* __restrict__ Wh,
                                               unsigned short* __restrict__ Afin,
                                               unsigned short* __restrict__ WaT,
                                               unsigned short* __restrict__ WrT,
                                               unsigned short* __restrict__ WzT,
                                               unsigned short* __restrict__ WhT) {
    int bid = blockIdx.x;
    int tid = threadIdx.x;
    if (bid < 2048) {
        size_t flat = ((size_t)bid * 256 + tid) * 4;
        float4 s4 = *(const float4*)(supports + flat);
        const float s7 = SKIPF * SKIPF * SKIPF * SKIPF * SKIPF * SKIPF * SKIPF; // 0.3^T0
        float a0 = s4.x * s7, a1 = s4.y * s7, a2 = s4.z * s7, a3 = s4.w * s7;
        #pragma unroll
        for (int t = T0; t < TT; ++t) {
            const unsigned short* p = AttA + ((size_t)t << 21) + flat;
            uint2 u = *(const uint2*)p;
            a0 = SKIPF * a0 + bf2f((unsigned short)(u.x & 0xffff));
            a1 = SKIPF * a1 + bf2f((unsigned short)(u.x >> 16));
            a2 = SKIPF * a2 + bf2f((unsigned short)(u.y & 0xffff));
            a3 = SKIPF * a3 + bf2f((unsigned short)(u.y >> 16));
        }
        uint2 o;
        o.x = pack2(f2bf(a0), f2bf(a1));
        o.y = pack2(f2bf(a2), f2bf(a3));
        *(uint2*)(Afin + flat) = o;
    } else {
        int idx = (bid - 2048) * 256 + tid;     // 0..32767
        if (idx < 16384) {
            int dout = idx >> 7, din = idx & 127;
            WaT[idx] = f2bf(Wa[(din << 7) + dout]);
        }
        {
            int dout = idx >> 8, dk = idx & 255;
            WrT[idx] = f2bf(Wr[(dk << 7) + dout]);
            WzT[idx] = f2bf(Wz[(dk << 7) + dout]);
            WhT[idx] = f2bf(Wh[(dk << 7) + dout]);
        }
    }
}

// ---------------------------------------------------------------------------
// gru5: FUSED hTinit + 5 GRU steps + fc. grid = 32 (one block per batch),
// 512 threads = 8 waves = 2 groups x 4 waves. Per step: 4 passes x 2
// concurrent 32-row tiles. h in GLOBAL double-buffer: same-block producers/
// consumers (same CU), __syncthreads gives visibility. Phases verbatim
// k_step. fc in-register at s==4. FIX (R22): hOut is pre-offset by b<<15,
// write index uses (col<<8) only (R21 double-added the batch offset).
// ---------------------------------------------------------------------------
__global__ __launch_bounds__(512) void k_gru5(
    const float* __restrict__ x15,
    const unsigned short* __restrict__ Afin,
    const unsigned short* __restrict__ WaT, const float* __restrict__ ba,
    const unsigned short* __restrict__ WrT, const float* __restrict__ br,
    const unsigned short* __restrict__ WzT, const float* __restrict__ bz,
    const unsigned short* __restrict__ WhT, const float* __restrict__ bh,
    const float* __restrict__ Wfc, const float* __restrict__ bfc,
    unsigned short* __restrict__ hA, unsigned short* __restrict__ hB,
    float* __restrict__ out) {

    int b = blockIdx.x;
    int tid = threadIdx.x;              // 0..511
    int wave = tid >> 6;                // 0..7
    int g = wave >> 2;                  // group 0/1
    int wv = wave & 3;                  // wave-in-group
    int lane = tid & 63;
    int m16 = lane & 15, quad = lane >> 4;
    int wcol = wv << 5;
    int gt = (wv << 6) | lane;          // group-local tid 0..255

    __shared__ unsigned short msgS[2][32 * 136];   // 17.0 KB
    __shared__ unsigned short ahS[2][32 * 264];    // 33.8 KB
    __shared__ float rf[8][2];

    // ---- prologue: hA[b] = bf16(x15[b]^T)  (hTinit, 2 tiles/iter) ----
    {
        float* tl = (float*)ahS;              // 2 x 32x33 f32 scratch (8.4 KB)
        int half = tid >> 8;                  // 0/1
        int t256 = tid & 255;
        int i = t256 >> 5, j = t256 & 31;
        float* tlh = tl + half * (32 * 33);
        for (int it = 0; it < 16; ++it) {
            int tile = (it << 1) + half;      // 0..31
            int d0 = (tile >> 3) << 5;
            int nn0 = (tile & 7) << 5;
            #pragma unroll
            for (int s4 = 0; s4 < 4; ++s4) {
                int nl = (s4 << 3) + i;
                tlh[nl * 33 + j] = x15[((size_t)(b * 256 + nn0 + nl) << 7) + d0 + j];
            }
            __syncthreads();
            #pragma unroll
            for (int s4 = 0; s4 < 4; ++s4) {
                int dd = (s4 << 3) + i;
                hA[((size_t)(b * 128 + d0 + dd) << 8) + nn0 + j] = f2bf(tlh[j * 33 + dd]);
            }
            __syncthreads();
        }
    }

    float fc0 = 0.f, fc1 = 0.f;

    for (int s = 0; s < NSTEPS; ++s) {
        const unsigned short* hIn = ((s & 1) ? hB : hA) + ((size_t)b << 15);
        unsigned short* hOut = ((s & 1) ? hA : hB) + ((size_t)b << 15);

        for (int p = 0; p < 4; ++p) {
            int rgp = (p << 1) + g;
            int n0 = rgp << 5;
            unsigned short* mS = msgS[g];
            unsigned short* aS = ahS[g];
            const unsigned short* Ab = Afin + ((size_t)b << 16) + ((size_t)n0 << 8);

            // stage h-half of aS (transpose: aS[row][128+d] = hIn[d][n0+row])
            #pragma unroll
            for (int j = 0; j < 16; ++j) {
                int idx = (j << 8) + gt;
                int d = idx >> 5, row = idx & 31;
                aS[row * 264 + 128 + d] = hIn[((size_t)d << 8) + n0 + row];
            }

            // ---- bmm: msg = A_tile @ h  (K=256) ----
            f32x4 acc[2][2];
            #pragma unroll
            for (int rb = 0; rb < 2; ++rb)
                #pragma unroll
                for (int cb = 0; cb < 2; ++cb) acc[rb][cb] = (f32x4){0.f, 0.f, 0.f, 0.f};

            #pragma unroll 2
            for (int ks = 0; ks < 8; ++ks) {
                bf16x8 af[2], bf[2];
                #pragma unroll
                for (int rb = 0; rb < 2; ++rb)
                    af[rb] = *(const bf16x8*)(Ab + (((rb << 4) + m16) << 8) + (ks << 5) + (quad << 3));
                #pragma unroll
                for (int cb = 0; cb < 2; ++cb)
                    bf[cb] = *(const bf16x8*)(hIn + ((wcol + (cb << 4) + m16) << 8) + (ks << 5) + (quad << 3));
                #pragma unroll
                for (int rb = 0; rb < 2; ++rb)
                    #pragma unroll
                    for (int cb = 0; cb < 2; ++cb)
                        acc[rb][cb] = __builtin_amdgcn_mfma_f32_16x16x32_bf16(af[rb], bf[cb], acc[rb][cb], 0, 0, 0);
            }
            #pragma unroll
            for (int rb = 0; rb < 2; ++rb)
                #pragma unroll
                for (int cb = 0; cb < 2; ++cb)
                    #pragma unroll
                    for (int r = 0; r < 4; ++r)
                        mS[((rb << 4) + (quad << 2) + r) * 136 + wcol + (cb << 4) + m16] = f2bf(acc[rb][cb][r]);
            __syncthreads();   // covers h-half staging too

            // ---- a = msg @ Wa + ba ----
            #pragma unroll
            for (int rb = 0; rb < 2; ++rb)
                #pragma unroll
                for (int cb = 0; cb < 2; ++cb) acc[rb][cb] = (f32x4){0.f, 0.f, 0.f, 0.f};
            #pragma unroll
            for (int ks = 0; ks < 4; ++ks) {
                bf16x8 af[2], bf[2];
                #pragma unroll
                for (int rb = 0; rb < 2; ++rb)
                    af[rb] = *(const bf16x8*)(mS + ((rb << 4) + m16) * 136 + (ks << 5) + (quad << 3));
                #pragma unroll
                for (int cb = 0; cb < 2; ++cb)
                    bf[cb] = *(const bf16x8*)(WaT + ((wcol + (cb << 4) + m16) << 7) + (ks << 5) + (quad << 3));
                #pragma unroll
                for (int rb = 0; rb < 2; ++rb)
                    #pragma unroll
                    for (int cb = 0; cb < 2; ++cb)
                        acc[rb][cb] = __builtin_amdgcn_mfma_f32_16x16x32_bf16(af[rb], bf[cb], acc[rb][cb], 0, 0, 0);
            }
            {
                float bav[2];
                #pragma unroll
                for (int cb = 0; cb < 2; ++cb) bav[cb] = ba[wcol + (cb << 4) + m16];
                #pragma unroll
                for (int rb = 0; rb < 2; ++rb)
                    #pragma unroll
                    for (int cb = 0; cb < 2; ++cb)
                        #pragma unroll
                        for (int r = 0; r < 4; ++r)
                            aS[((rb << 4) + (quad << 2) + r) * 264 + wcol + (cb << 4) + m16] =
                                f2bf(acc[rb][cb][r] + bav[cb]);
            }
            __syncthreads();

            // h_old
            float hv[2][2][4];
            #pragma unroll
            for (int rb = 0; rb < 2; ++rb)
                #pragma unroll
                for (int cb = 0; cb < 2; ++cb) {
                    int col = wcol + (cb << 4) + m16;
                    uint2 u = *(const uint2*)(hIn + ((size_t)col << 8) + n0 + (rb << 4) + (quad << 2));
                    hv[rb][cb][0] = bf2f((unsigned short)(u.x & 0xffff));
                    hv[rb][cb][1] = bf2f((unsigned short)(u.x >> 16));
                    hv[rb][cb][2] = bf2f((unsigned short)(u.y & 0xffff));
                    hv[rb][cb][3] = bf2f((unsigned short)(u.y >> 16));
                }

            // ---- r and z ----
            f32x4 racc[2][2], zacc[2][2];
            #pragma unroll
            for (int rb = 0; rb < 2; ++rb)
                #pragma unroll
                for (int cb = 0; cb < 2; ++cb) {
                    racc[rb][cb] = (f32x4){0.f, 0.f, 0.f, 0.f};
                    zacc[rb][cb] = (f32x4){0.f, 0.f, 0.f, 0.f};
                }
            #pragma unroll 2
            for (int ks = 0; ks < 8; ++ks) {
                bf16x8 af[2], bfr[2], bfz[2];
                #pragma unroll
                for (int rb = 0; rb < 2; ++rb)
                    af[rb] = *(const bf16x8*)(aS + ((rb << 4) + m16) * 264 + (ks << 5) + (quad << 3));
                #pragma unroll
                for (int cb = 0; cb < 2; ++cb) {
                    int dout = wcol + (cb << 4) + m16;
                    bfr[cb] = *(const bf16x8*)(WrT + (dout << 8) + (ks << 5) + (quad << 3));
                    bfz[cb] = *(const bf16x8*)(WzT + (dout << 8) + (ks << 5) + (quad << 3));
                }
                #pragma unroll
                for (int rb = 0; rb < 2; ++rb)
                    #pragma unroll
                    for (int cb = 0; cb < 2; ++cb) {
                        racc[rb][cb] = __builtin_amdgcn_mfma_f32_16x16x32_bf16(af[rb], bfr[cb], racc[rb][cb], 0, 0, 0);
                        zacc[rb][cb] = __builtin_amdgcn_mfma_f32_16x16x32_bf16(af[rb], bfz[cb], zacc[rb][cb], 0, 0, 0);
                    }
            }
            float zv[2][2][4];
            {
                float brv[2], bzv[2];
                #pragma unroll
                for (int cb = 0; cb < 2; ++cb) {
                    brv[cb] = br[wcol + (cb << 4) + m16];
                    bzv[cb] = bz[wcol + (cb << 4) + m16];
                }
                #pragma unroll
                for (int rb = 0; rb < 2; ++rb)
                    #pragma unroll
                    for (int cb = 0; cb < 2; ++cb)
                        #pragma unroll
                        for (int r = 0; r < 4; ++r) {
                            racc[rb][cb][r] = sigmoidf_(racc[rb][cb][r] + brv[cb]);
                            zv[rb][cb][r]  = sigmoidf_(zacc[rb][cb][r] + bzv[cb]);
                        }
            }
            __syncthreads();   // all aS reads done -> safe to overwrite h-half

            #pragma unroll
            for (int rb = 0; rb < 2; ++rb)
                #pragma unroll
                for (int cb = 0; cb < 2; ++cb)
                    #pragma unroll
                    for (int r = 0; r < 4; ++r)
                        aS[((rb << 4) + (quad << 2) + r) * 264 + 128 + wcol + (cb << 4) + m16] =
                            f2bf(racc[rb][cb][r] * hv[rb][cb][r]);
            __syncthreads();

            // ---- h_tilde ----
            #pragma unroll
            for (int rb = 0; rb < 2; ++rb)
                #pragma unroll
                for (int cb = 0; cb < 2; ++cb) acc[rb][cb] = (f32x4){0.f, 0.f, 0.f, 0.f};
            #pragma unroll 2
            for (int ks = 0; ks < 8; ++ks) {
                bf16x8 af[2], bf[2];
                #pragma unroll
                for (int rb = 0; rb < 2; ++rb)
                    af[rb] = *(const bf16x8*)(aS + ((rb << 4) + m16) * 264 + (ks << 5) + (quad << 3));
                #pragma unroll
                for (int cb = 0; cb < 2; ++cb)
                    bf[cb] = *(const bf16x8*)(WhT + ((wcol + (cb << 4) + m16) << 8) + (ks << 5) + (quad << 3));
                #pragma unroll
                for (int rb = 0; rb < 2; ++rb)
                    #pragma unroll
                    for (int cb = 0; cb < 2; ++cb)
                        acc[rb][cb] = __builtin_amdgcn_mfma_f32_16x16x32_bf16(af[rb], bf[cb], acc[rb][cb], 0, 0, 0);
            }

            // ---- update: write hOut (s<4) or accumulate fc (s==4) ----
            {
                float bhv[2];
                #pragma unroll
                for (int cb = 0; cb < 2; ++cb) bhv[cb] = bh[wcol + (cb << 4) + m16];
                #pragma unroll
                for (int rb = 0; rb < 2; ++rb)
                    #pragma unroll
                    for (int cb = 0; cb < 2; ++cb) {
                        int col = wcol + (cb << 4) + m16;
                        unsigned short pk[4];
                        #pragma unroll
                        for (int r = 0; r < 4; ++r) {
                            float ht = tanhf_(acc[rb][cb][r] + bhv[cb]);
                            float hn = hv[rb][cb][r] + zv[rb][cb][r] * (ht - hv[rb][cb][r]);
                            pk[r] = f2bf(hn);
                        }
                        if (s < NSTEPS - 1) {
                            uint2 pw;
                            pw.x = pack2(pk[0], pk[1]); pw.y = pack2(pk[2], pk[3]);
                            // FIX: hOut already offset by b<<15 -> index by col only
                            *(uint2*)(hOut + ((size_t)col << 8) + n0 + (rb << 4) + (quad << 2)) = pw;
                        } else {
                            #pragma unroll
                            for (int r = 0; r < 4; ++r) {
                                int nn = n0 + (rb << 4) + (quad << 2) + r;
                                float hval = bf2f(pk[r]);
                                const float2 w = *(const float2*)(Wfc + (size_t)(nn * 128 + col) * 2);
                                fc0 = fmaf(hval, w.x, fc0);
                                fc1 = fmaf(hval, w.y, fc1);
                            }
                        }
                    }
            }
            __syncthreads();   // pass end: aS free for next pass; hOut drained
        }
    }

    // ---- fc reduce over the block ----
    #pragma unroll
    for (int off = 32; off; off >>= 1) {
        fc0 += __shfl_down(fc0, off, 64);
        fc1 += __shfl_down(fc1, off, 64);
    }
    if (lane == 0) { rf[wave][0] = fc0; rf[wave][1] = fc1; }
    __syncthreads();
    if (tid == 0) {
        float s0 = 0.f, s1 = 0.f;
        #pragma unroll
        for (int w = 0; w < 8; ++w) { s0 += rf[w][0]; s1 += rf[w][1]; }
        out[b * 2 + 0] = s0 + bfc[0];
        out[b * 2 + 1] = s1 + bfc[1];
    }
}

// ---------------------------------------------------------------------------
extern "C" void kernel_launch(void* const* d_in, const int* in_sizes, int n_in,
                              void* d_out, int out_size, void* d_ws, size_t ws_size,
                              hipStream_t stream) {
    const float* x_all    = (const float*)d_in[0];
    const float* supports = (const float*)d_in[1];
    const float* Wgl = (const float*)d_in[2];
    const float* Wa  = (const float*)d_in[3];
    const float* ba  = (const float*)d_in[4];
    const float* Wr  = (const float*)d_in[5];
    const float* br  = (const float*)d_in[6];
    const float* Wz  = (const float*)d_in[7];
    const float* bz  = (const float*)d_in[8];
    const float* Wh  = (const float*)d_in[9];
    const float* bh  = (const float*)d_in[10];
    const float* Wfc = (const float*)d_in[11];
    const float* bfc = (const float*)d_in[12];
    float* out = (float*)d_out;

    char* p = (char*)d_ws;
    auto alloc = [&](size_t bytes) { char* r = p; p += (bytes + 255) & ~(size_t)255; return r; };

    unsigned short* AttA = (unsigned short*)alloc((size_t)TT * BB * NN * NN * 2);  // 64 MB
    unsigned short* Afin = (unsigned short*)alloc((size_t)BB * NN * NN * 2);       // 4 MB
    unsigned short* hT0  = (unsigned short*)alloc((size_t)BB * DD * NN * 2);       // 2 MB
    unsigned short* hT1  = (unsigned short*)alloc((size_t)BB * DD * NN * 2);       // 2 MB
    unsigned short* WaT  = (unsigned short*)alloc(128 * 128 * 2);
    unsigned short* WrT  = (unsigned short*)alloc(256 * 128 * 2);
    unsigned short* WzT  = (unsigned short*)alloc(256 * 128 * 2);
    unsigned short* WhT  = (unsigned short*)alloc(256 * 128 * 2);
    // total ~72.5 MB

    // 1. attention gram (in-block norms, f32 direct), live timesteps only
    k_gram2<<<4 * TBLIVE, 256, 0, stream>>>(x_all, Wgl, AttA);

    // 2. scan + wprep (merged)
    k_scanh<<<2048 + 128, 256, 0, stream>>>(supports, AttA,
                                            Wa, Wr, Wz, Wh,
                                            Afin, WaT, WrT, WzT, WhT);

    // 3. fused GRU: hTinit + 5 steps + fc, one block per batch
    const float* x15 = x_all + (size_t)15 * BB * NN * DD;
    k_gru5<<<BB, 512, 0, stream>>>(x15, Afin,
                                   WaT, ba, WrT, br, WzT, bz, WhT, bh,
                                   Wfc, bfc, hT0, hT1, out);
}